// Round 2
// baseline (1288.725 us; speedup 1.0000x reference)
//
#include <hip/hip_runtime.h>
#include <hip/hip_bf16.h>
#include <stdint.h>
#include <math.h>

#define DIM   1024
#define SEQ   2048
#define BATCH 8

typedef __attribute__((ext_vector_type(8))) short short8;
typedef __attribute__((ext_vector_type(4))) float floatx4;

__device__ __forceinline__ uint2 pack4bf(float a, float b, float c, float d) {
    union { __hip_bfloat162 h; unsigned u; } p0, p1;
    p0.h = __float22bfloat162_rn(float2{a, b});
    p1.h = __float22bfloat162_rn(float2{c, d});
    return uint2{p0.u, p1.u};
}

// out[m,n] = sum_d (X[m,d] + ctx[d]) * W[n,d] + bias[n], output bf16.
// transpose_out=0: out is [B*S, D] row-major. transpose_out=1: out is [B, D, S] (vT).
__global__ __launch_bounds__(256, 2) void proj_kernel(
    const float* __restrict__ X, const float* __restrict__ ctx,
    const float* __restrict__ W, const float* __restrict__ bias,
    unsigned short* __restrict__ out, int transpose_out, int use_ctx)
{
    __shared__ unsigned short As[128 * 40];  // stride 40: 16B-aligned rows
    __shared__ unsigned short Bs[128 * 40];

    const int tid  = threadIdx.x;
    const int lane = tid & 63;
    const int wave = tid >> 6;
    const int quad = lane >> 4;
    const int l16  = lane & 15;
    const int wy = wave >> 1, wx = wave & 1;
    const int row0 = blockIdx.x * 128;
    const int col0 = blockIdx.y * 128;

    floatx4 acc[4][4];
#pragma unroll
    for (int i = 0; i < 4; ++i)
#pragma unroll
        for (int j = 0; j < 4; ++j)
            acc[i][j] = (floatx4){0.f, 0.f, 0.f, 0.f};

    const int sr = tid >> 3;         // 0..31
    const int sc = (tid & 7) << 2;   // 0,4,...,28

    // software pipeline: prefetch tile k0 into registers
    float4 pa[4], pb[4], pc;
#pragma unroll
    for (int p = 0; p < 4; ++p) {
        const int r = sr + p * 32;
        pa[p] = *(const float4*)&X[(size_t)(row0 + r) * DIM + sc];
        pb[p] = *(const float4*)&W[(size_t)(col0 + r) * DIM + sc];
    }
    pc = use_ctx ? *(const float4*)&ctx[sc] : (float4){0.f, 0.f, 0.f, 0.f};

    for (int k0 = 0; k0 < DIM; k0 += 32) {
        // ---- convert + store current tile to LDS ----
#pragma unroll
        for (int p = 0; p < 4; ++p) {
            const int r = sr + p * 32;
            *(uint2*)&As[r * 40 + sc] =
                pack4bf(pa[p].x + pc.x, pa[p].y + pc.y, pa[p].z + pc.z, pa[p].w + pc.w);
            *(uint2*)&Bs[r * 40 + sc] = pack4bf(pb[p].x, pb[p].y, pb[p].z, pb[p].w);
        }
        __syncthreads();

        // ---- prefetch next tile (overlaps ds_read + MFMA below) ----
        const int kn = (k0 + 32 < DIM) ? (k0 + 32) : k0;
#pragma unroll
        for (int p = 0; p < 4; ++p) {
            const int r = sr + p * 32;
            pa[p] = *(const float4*)&X[(size_t)(row0 + r) * DIM + kn + sc];
            pb[p] = *(const float4*)&W[(size_t)(col0 + r) * DIM + kn + sc];
        }
        if (use_ctx) pc = *(const float4*)&ctx[kn + sc];

        // ---- fragments + MFMA ----
        short8 af[4], bfr[4];
#pragma unroll
        for (int t = 0; t < 4; ++t) {
            af[t]  = *(const short8*)&As[(wy * 64 + t * 16 + l16) * 40 + quad * 8];
            bfr[t] = *(const short8*)&Bs[(wx * 64 + t * 16 + l16) * 40 + quad * 8];
        }
#pragma unroll
        for (int mt = 0; mt < 4; ++mt)
#pragma unroll
            for (int nt = 0; nt < 4; ++nt)
                acc[mt][nt] = __builtin_amdgcn_mfma_f32_16x16x32_bf16(
                    af[mt], bfr[nt], acc[mt][nt], 0, 0, 0);
        __syncthreads();
    }

    // epilogue: + bias, store bf16. C/D layout: col = l16, row = quad*4 + reg.
#pragma unroll
    for (int nt = 0; nt < 4; ++nt) {
        const int n = col0 + wx * 64 + nt * 16 + l16;
        const float bz = bias[n];
#pragma unroll
        for (int mt = 0; mt < 4; ++mt) {
            const int mbase = row0 + wy * 64 + mt * 16 + quad * 4;
            const floatx4 a = acc[mt][nt];
            if (!transpose_out) {
#pragma unroll
                for (int rg = 0; rg < 4; ++rg) {
                    union { __hip_bfloat16 h; unsigned short u; } cv;
                    cv.h = __float2bfloat16(a[rg] + bz);
                    out[(size_t)(mbase + rg) * DIM + n] = cv.u;
                }
            } else {
                const int bb = mbase >> 11;          // /SEQ
                const int ss = mbase & (SEQ - 1);    // consecutive s for reg 0..3
                *(uint2*)&out[((size_t)bb * DIM + n) * SEQ + ss] =
                    pack4bf(a[0] + bz, a[1] + bz, a[2] + bz, a[3] + bz);
            }
        }
    }
}

// Flash attention, causal, single head, head-dim 1024.
// Block: 256 threads (4 waves). 32 Q-rows per block, Bc=32 keys/iter.
// Waves split D into 4 chunks of 256 (partial QK^T reduce via LDS; PV output cols).
// Pipelined: Q resident in regs; K double-buffered (j+1 issued during softmax of j);
// V fragments issued at iter top, consumed after 2 barriers.
__global__ __launch_bounds__(256, 1) void attn_kernel(
    const unsigned short* __restrict__ Q, const unsigned short* __restrict__ K,
    const unsigned short* __restrict__ VT, float* __restrict__ out)
{
    __shared__ float Sp[4][32][36];
    __shared__ unsigned short Pl[32 * 40];
    __shared__ float mS[32], lS[32], aS[32];

    const int tid  = threadIdx.x;
    const int lane = tid & 63;
    const int wave = tid >> 6;
    const int quad = lane >> 4;
    const int l16  = lane & 15;

    // work-balanced remap: (q, q+32) pairs sum to ~const causal work
    const int f    = blockIdx.x;
    const int by   = f & 7;
    const int qRaw = f >> 3;                                   // 0..63
    const int qb   = (qRaw < 32) ? (2 * qRaw) : (127 - 2 * qRaw);
    const int q0   = qb * 32;

    if (tid < 32) { mS[tid] = -INFINITY; lS[tid] = 0.f; aS[tid] = 0.f; }
    __syncthreads();

    floatx4 o[2][16];
#pragma unroll
    for (int mt = 0; mt < 2; ++mt)
#pragma unroll
        for (int nt = 0; nt < 16; ++nt)
            o[mt][nt] = (floatx4){0.f, 0.f, 0.f, 0.f};

    const int rr = tid >> 3;        // softmax row 0..31
    const int c0 = (tid & 7) << 2;  // softmax col group

    const size_t qrow = (size_t)by * SEQ;
    const size_t vrow = (size_t)by * DIM;

    // ---- Q resident: this wave's 32x256 chunk, loaded once ----
    short8 qa[2][8];
#pragma unroll
    for (int mt = 0; mt < 2; ++mt)
#pragma unroll
        for (int ks = 0; ks < 8; ++ks)
            qa[mt][ks] = *(const short8*)
                &Q[(qrow + q0 + mt * 16 + l16) * DIM + wave * 256 + ks * 32 + quad * 8];

    short8 kA[2][8], kB[2][8];
#pragma unroll
    for (int nt = 0; nt < 2; ++nt)
#pragma unroll
        for (int ks = 0; ks < 8; ++ks)
            kA[nt][ks] = *(const short8*)
                &K[(qrow + nt * 16 + l16) * DIM + wave * 256 + ks * 32 + quad * 8];

    auto iter = [&](int j, short8 (&kcur)[2][8], short8 (&knxt)[2][8]) {
        // ---- V fragments for this iter: issue first, consume after 2 barriers ----
        short8 vb[16];
#pragma unroll
        for (int nt = 0; nt < 16; ++nt)
            vb[nt] = *(const short8*)
                &VT[(vrow + wave * 256 + nt * 16 + l16) * SEQ + j * 32 + quad * 8];

        // ---- QK^T partial over this wave's 256-wide D chunk ----
        floatx4 sp[2][2];
#pragma unroll
        for (int mt = 0; mt < 2; ++mt)
#pragma unroll
            for (int nt = 0; nt < 2; ++nt)
                sp[mt][nt] = (floatx4){0.f, 0.f, 0.f, 0.f};
#pragma unroll
        for (int ks = 0; ks < 8; ++ks)
#pragma unroll
            for (int mt = 0; mt < 2; ++mt)
#pragma unroll
                for (int nt = 0; nt < 2; ++nt)
                    sp[mt][nt] = __builtin_amdgcn_mfma_f32_16x16x32_bf16(
                        qa[mt][ks], kcur[nt][ks], sp[mt][nt], 0, 0, 0);
#pragma unroll
        for (int mt = 0; mt < 2; ++mt)
#pragma unroll
            for (int nt = 0; nt < 2; ++nt)
#pragma unroll
                for (int rg = 0; rg < 4; ++rg)
                    Sp[wave][mt * 16 + quad * 4 + rg][nt * 16 + l16] = sp[mt][nt][rg];
        __syncthreads();

        // ---- K prefetch for j+1 (covered by softmax phase) ----
        const int jn = (j < qb) ? j + 1 : j;
#pragma unroll
        for (int nt = 0; nt < 2; ++nt)
#pragma unroll
            for (int ks = 0; ks < 8; ++ks)
                knxt[nt][ks] = *(const short8*)
                    &K[(qrow + jn * 32 + nt * 16 + l16) * DIM + wave * 256 + ks * 32 + quad * 8];

        // ---- reduce partials + online softmax (8 threads per row) ----
        const float4 t0 = *(const float4*)&Sp[0][rr][c0];
        const float4 t1 = *(const float4*)&Sp[1][rr][c0];
        const float4 t2 = *(const float4*)&Sp[2][rr][c0];
        const float4 t3 = *(const float4*)&Sp[3][rr][c0];
        float s0 = (t0.x + t1.x + t2.x + t3.x) * 0.03125f;
        float s1 = (t0.y + t1.y + t2.y + t3.y) * 0.03125f;
        float s2 = (t0.z + t1.z + t2.z + t3.z) * 0.03125f;
        float s3 = (t0.w + t1.w + t2.w + t3.w) * 0.03125f;
        if (j == qb) {
            if (c0 + 0 > rr) s0 = -INFINITY;
            if (c0 + 1 > rr) s1 = -INFINITY;
            if (c0 + 2 > rr) s2 = -INFINITY;
            if (c0 + 3 > rr) s3 = -INFINITY;
        }
        float mx = fmaxf(fmaxf(s0, s1), fmaxf(s2, s3));
#pragma unroll
        for (int off = 1; off < 8; off <<= 1) mx = fmaxf(mx, __shfl_xor(mx, off));
        const float mold = mS[rr];
        const float mnew = fmaxf(mold, mx);
        const float p0 = __expf(s0 - mnew), p1 = __expf(s1 - mnew);
        const float p2 = __expf(s2 - mnew), p3 = __expf(s3 - mnew);
        float rs = p0 + p1 + p2 + p3;
#pragma unroll
        for (int off = 1; off < 8; off <<= 1) rs += __shfl_xor(rs, off);
        const float alpha = __expf(mold - mnew);
        if ((tid & 7) == 0) {
            mS[rr] = mnew;
            lS[rr] = lS[rr] * alpha + rs;
            aS[rr] = alpha;
        }
        *(uint2*)&Pl[rr * 40 + c0] = pack4bf(p0, p1, p2, p3);
        __syncthreads();

        // ---- PV over this wave's 256 output cols ----
        short8 pa[2];
#pragma unroll
        for (int mt = 0; mt < 2; ++mt)
            pa[mt] = *(const short8*)&Pl[(mt * 16 + l16) * 40 + quad * 8];
        float al[2][4];
#pragma unroll
        for (int mt = 0; mt < 2; ++mt)
#pragma unroll
            for (int rg = 0; rg < 4; ++rg)
                al[mt][rg] = aS[mt * 16 + quad * 4 + rg];
#pragma unroll
        for (int mt = 0; mt < 2; ++mt)
#pragma unroll
            for (int nt = 0; nt < 16; ++nt)
#pragma unroll
                for (int rg = 0; rg < 4; ++rg)
                    o[mt][nt][rg] *= al[mt][rg];
#pragma unroll
        for (int nt = 0; nt < 16; ++nt)
#pragma unroll
            for (int mt = 0; mt < 2; ++mt)
                o[mt][nt] = __builtin_amdgcn_mfma_f32_16x16x32_bf16(
                    pa[mt], vb[nt], o[mt][nt], 0, 0, 0);
        // no barrier needed: next iter's pre-barrier writes (Sp) don't alias Pl/aS.
    };

    int j = 0;
    for (;;) {
        iter(j, kA, kB);
        if (++j > qb) break;
        iter(j, kB, kA);
        if (++j > qb) break;
    }

    float linv[2][4];
#pragma unroll
    for (int mt = 0; mt < 2; ++mt)
#pragma unroll
        for (int rg = 0; rg < 4; ++rg)
            linv[mt][rg] = 1.0f / lS[mt * 16 + quad * 4 + rg];
#pragma unroll
    for (int mt = 0; mt < 2; ++mt)
#pragma unroll
        for (int nt = 0; nt < 16; ++nt)
#pragma unroll
            for (int rg = 0; rg < 4; ++rg)
                out[(qrow + q0 + mt * 16 + quad * 4 + rg) * DIM + wave * 256 + nt * 16 + l16]
                    = o[mt][nt][rg] * linv[mt][rg];
}

extern "C" void kernel_launch(void* const* d_in, const int* in_sizes, int n_in,
                              void* d_out, int out_size, void* d_ws, size_t ws_size,
                              hipStream_t stream) {
    const float* query = (const float*)d_in[0];
    const float* key   = (const float*)d_in[1];
    const float* value = (const float*)d_in[2];
    const float* ctx   = (const float*)d_in[3];
    const float* Wq    = (const float*)d_in[4];
    const float* bq    = (const float*)d_in[5];
    const float* Wk    = (const float*)d_in[6];
    const float* bk    = (const float*)d_in[7];
    const float* Wv    = (const float*)d_in[8];
    const float* bv    = (const float*)d_in[9];

    const size_t BSD = (size_t)BATCH * SEQ * DIM;
    unsigned short* qw = (unsigned short*)d_ws;   // [B,S,D] bf16
    unsigned short* kw = qw + BSD;                // [B,S,D] bf16
    unsigned short* vw = kw + BSD;                // [B,D,S] bf16 (transposed)
    float* out = (float*)d_out;

    const dim3 pg((BATCH * SEQ) / 128, DIM / 128);  // (128, 8)
    const dim3 pb(256);
    proj_kernel<<<pg, pb, 0, stream>>>(query, ctx, Wq, bq, qw, 0, 1);
    proj_kernel<<<pg, pb, 0, stream>>>(key,   ctx, Wk, bk, kw, 0, 1);
    proj_kernel<<<pg, pb, 0, stream>>>(value, ctx, Wv, bv, vw, 1, 0);

    attn_kernel<<<dim3(BATCH * (SEQ / 32)), dim3(256), 0, stream>>>(qw, kw, vw, out);
}

// Round 3
// 769.395 us; speedup vs baseline: 1.6750x; 1.6750x over previous
//
#include <hip/hip_runtime.h>
#include <hip/hip_bf16.h>
#include <stdint.h>
#include <math.h>

#define DIM   1024
#define SEQ   2048
#define BATCH 8
#define BSD   (BATCH * SEQ * DIM)      // 16777216
#define DD    (DIM * DIM)              // 1048576

typedef __attribute__((ext_vector_type(8))) short short8;
typedef __attribute__((ext_vector_type(4))) float floatx4;
typedef unsigned int u32;
typedef unsigned short ushort_t;

#define GLOAD_LDS16(gptr, lptr)                                                   \
    __builtin_amdgcn_global_load_lds(                                             \
        (const __attribute__((address_space(1))) u32*)(gptr),                     \
        (__attribute__((address_space(3))) u32*)(lptr), 16, 0, 0)

__device__ __forceinline__ uint2 pack4bf(float a, float b, float c, float d) {
    union { __hip_bfloat162 h; unsigned u; } p0, p1;
    p0.h = __float22bfloat162_rn(float2{a, b});
    p1.h = __float22bfloat162_rn(float2{c, d});
    return uint2{p0.u, p1.u};
}

// ---------------- fp32 -> bf16 convert (ctx folded into q/k inputs) -----------
__global__ __launch_bounds__(256) void convert_kernel(
    const float* __restrict__ q, const float* __restrict__ k, const float* __restrict__ v,
    const float* __restrict__ ctx,
    const float* __restrict__ Wq, const float* __restrict__ Wk, const float* __restrict__ Wv,
    ushort_t* __restrict__ xq, ushort_t* __restrict__ xk, ushort_t* __restrict__ xv,
    ushort_t* __restrict__ wq, ushort_t* __restrict__ wk, ushort_t* __restrict__ wv)
{
    const long idx = (long)blockIdx.x * 256 + threadIdx.x;
    const long T  = BSD / 4;   // 2^22 float4 groups per tensor
    const long W4 = DD / 4;    // 2^18
    if (idx < 3 * T) {
        const int  seg = (int)(idx >> 22);
        const long off = idx & (T - 1);
        const float* src = (seg == 0) ? q : (seg == 1) ? k : v;
        ushort_t*    dst = (seg == 0) ? xq : (seg == 1) ? xk : xv;
        float4 x = ((const float4*)src)[off];
        if (seg < 2) {
            const float4 c = ((const float4*)ctx)[off & (DIM / 4 - 1)];
            x.x += c.x; x.y += c.y; x.z += c.z; x.w += c.w;
        }
        ((uint2*)dst)[off] = pack4bf(x.x, x.y, x.z, x.w);
    } else {
        const long r   = idx - 3 * T;
        const int  seg = (int)(r >> 18);
        const long off = r & (W4 - 1);
        const float* src = (seg == 0) ? Wq : (seg == 1) ? Wk : Wv;
        ushort_t*    dst = (seg == 0) ? wq : (seg == 1) ? wk : wv;
        const float4 x = ((const float4*)src)[off];
        ((uint2*)dst)[off] = pack4bf(x.x, x.y, x.z, x.w);
    }
}

// ---------------- bf16 NT GEMM, m97-style (global_load_lds w=16) --------------
// out[m,n] = sum_d X[m,d]*W[n,d] + bias[n].
// transpose_out=0: out [B*S, D] bf16 row-major; =1: out [B, D, S] bf16 (vT).
__global__ __launch_bounds__(256) void gemm_bf16(
    const ushort_t* __restrict__ X, const ushort_t* __restrict__ W,
    const float* __restrict__ bias, ushort_t* __restrict__ out, int transpose_out)
{
    __shared__ ushort_t As[128 * 64];   // linear, no pad (global_load_lds constraint)
    __shared__ ushort_t Bs[128 * 64];

    const int tid  = threadIdx.x;
    const int lane = tid & 63;
    const int wave = tid >> 6;
    const int quad = lane >> 4;
    const int l16  = lane & 15;
    const int wy = wave >> 1, wx = wave & 1;
    const int row0 = blockIdx.x * 128;
    const int col0 = blockIdx.y * 128;

    floatx4 acc[4][4];
#pragma unroll
    for (int i = 0; i < 4; ++i)
#pragma unroll
        for (int j = 0; j < 4; ++j)
            acc[i][j] = (floatx4){0.f, 0.f, 0.f, 0.f};

    const int srow = lane >> 3;         // 0..7 within slot
    const int scol = (lane & 7) * 8;    // ushort offset, 16B granules

    for (int k0 = 0; k0 < DIM; k0 += 64) {
#pragma unroll
        for (int i = 0; i < 4; ++i) {
            const int slot = wave * 4 + i;          // 0..15, 8 rows each
            const int grow = slot * 8 + srow;
            GLOAD_LDS16(&X[(size_t)(row0 + grow) * DIM + k0 + scol],
                        &As[slot * 512 + lane * 8]);
            GLOAD_LDS16(&W[(size_t)(col0 + grow) * DIM + k0 + scol],
                        &Bs[slot * 512 + lane * 8]);
        }
        __syncthreads();

        short8 af[4][2], bfr[4][2];
#pragma unroll
        for (int t = 0; t < 4; ++t)
#pragma unroll
            for (int ks = 0; ks < 2; ++ks) {
                af[t][ks]  = *(const short8*)&As[(wy * 64 + t * 16 + l16) * 64 + ks * 32 + quad * 8];
                bfr[t][ks] = *(const short8*)&Bs[(wx * 64 + t * 16 + l16) * 64 + ks * 32 + quad * 8];
            }
#pragma unroll
        for (int ks = 0; ks < 2; ++ks)
#pragma unroll
            for (int mt = 0; mt < 4; ++mt)
#pragma unroll
                for (int nt = 0; nt < 4; ++nt)
                    acc[mt][nt] = __builtin_amdgcn_mfma_f32_16x16x32_bf16(
                        af[mt][ks], bfr[nt][ks], acc[mt][nt], 0, 0, 0);
        __syncthreads();
    }

    // epilogue: +bias, bf16 store. C/D: col=l16, row=quad*4+reg.
#pragma unroll
    for (int nt = 0; nt < 4; ++nt) {
        const int n = col0 + wx * 64 + nt * 16 + l16;
        const float bz = bias[n];
#pragma unroll
        for (int mt = 0; mt < 4; ++mt) {
            const int mbase = row0 + wy * 64 + mt * 16 + quad * 4;
            const floatx4 a = acc[mt][nt];
            if (!transpose_out) {
#pragma unroll
                for (int rg = 0; rg < 4; ++rg) {
                    union { __hip_bfloat16 h; ushort_t u; } cv;
                    cv.h = __float2bfloat16(a[rg] + bz);
                    out[(size_t)(mbase + rg) * DIM + n] = cv.u;
                }
            } else {
                const int bb = mbase >> 11;          // /SEQ
                const int ss = mbase & (SEQ - 1);
                *(uint2*)&out[((size_t)bb * DIM + n) * SEQ + ss] =
                    pack4bf(a[0] + bz, a[1] + bz, a[2] + bz, a[3] + bz);
            }
        }
    }
}

// ---------------- flash attention, causal, Br=64, Bc=32, 8 waves --------------
// Wave w: QK^T over D-chunk [w*128, w*128+128); PV over out-cols same chunk.
// No redundant K/V reads. Partials reduced via LDS. 1 block/CU (VGPR-capped).
__global__ __launch_bounds__(512, 2) void attn_kernel(
    const ushort_t* __restrict__ Q, const ushort_t* __restrict__ K,
    const ushort_t* __restrict__ VT, float* __restrict__ out)
{
    __shared__ float Sp[8 * 64 * 40];        // [wave][row 64][col 32 pad 40] fp32
    __shared__ ushort_t Pl[64 * 40];         // P bf16, A-frag layout
    __shared__ float mS[64], lS[64], aS[64];

    const int tid  = threadIdx.x;
    const int lane = tid & 63;
    const int wave = tid >> 6;               // 0..7 = D-chunk
    const int quad = lane >> 4;
    const int l16  = lane & 15;

    const int by = blockIdx.x & 7;           // batch <-> XCD affinity
    const int t  = blockIdx.x >> 3;          // q-tile 0..31 (64 rows)
    const int q0 = t * 64;
    const int jmax = 2 * t + 1;              // Bc=32 k-tiles

    if (tid < 64) { mS[tid] = -INFINITY; lS[tid] = 0.f; aS[tid] = 0.f; }
    __syncthreads();

    const size_t qrow = (size_t)by * SEQ;
    const size_t vrow = (size_t)by * DIM;
    const int dchunk = wave * 128;

    // resident Q fragments: 64 rows x 128 cols for this wave  (64 VGPRs)
    short8 qa[4][4];
#pragma unroll
    for (int mt = 0; mt < 4; ++mt)
#pragma unroll
        for (int ks = 0; ks < 4; ++ks)
            qa[mt][ks] = *(const short8*)
                &Q[(qrow + q0 + mt * 16 + l16) * DIM + dchunk + ks * 32 + quad * 8];

    floatx4 o[4][8];                         // 64 rows x 128 cols  (128 VGPRs)
#pragma unroll
    for (int mt = 0; mt < 4; ++mt)
#pragma unroll
        for (int nt = 0; nt < 8; ++nt)
            o[mt][nt] = (floatx4){0.f, 0.f, 0.f, 0.f};

    const int rr = tid >> 3;                 // softmax row 0..63
    const int c0 = (tid & 7) << 2;           // col group

    for (int j = 0; j <= jmax; ++j) {
        // ---- K fragments for this wave's D-chunk (32 VGPRs, transient) ----
        short8 kb[2][4];
#pragma unroll
        for (int nt = 0; nt < 2; ++nt)
#pragma unroll
            for (int ks = 0; ks < 4; ++ks)
                kb[nt][ks] = *(const short8*)
                    &K[(qrow + j * 32 + nt * 16 + l16) * DIM + dchunk + ks * 32 + quad * 8];

        // ---- QK^T partial, per-mt to cap register peak ----
#pragma unroll
        for (int mt = 0; mt < 4; ++mt) {
            floatx4 s0 = (floatx4){0.f, 0.f, 0.f, 0.f};
            floatx4 s1 = (floatx4){0.f, 0.f, 0.f, 0.f};
#pragma unroll
            for (int ks = 0; ks < 4; ++ks) {
                s0 = __builtin_amdgcn_mfma_f32_16x16x32_bf16(qa[mt][ks], kb[0][ks], s0, 0, 0, 0);
                s1 = __builtin_amdgcn_mfma_f32_16x16x32_bf16(qa[mt][ks], kb[1][ks], s1, 0, 0, 0);
            }
#pragma unroll
            for (int rg = 0; rg < 4; ++rg) {
                const int row = mt * 16 + quad * 4 + rg;
                Sp[(wave * 64 + row) * 40 + l16]      = s0[rg];
                Sp[(wave * 64 + row) * 40 + 16 + l16] = s1[rg];
            }
        }
        __syncthreads();

        // ---- V prefetch (consumed in PV; latency covered by softmax) ----
        short8 vb[8];
#pragma unroll
        for (int nt = 0; nt < 8; ++nt)
            vb[nt] = *(const short8*)
                &VT[(vrow + dchunk + nt * 16 + l16) * SEQ + j * 32 + quad * 8];

        // ---- reduce 8 partials + online softmax (8 threads per row) ----
        float4 s = {0.f, 0.f, 0.f, 0.f};
#pragma unroll
        for (int w = 0; w < 8; ++w) {
            const float4 p = *(const float4*)&Sp[(w * 64 + rr) * 40 + c0];
            s.x += p.x; s.y += p.y; s.z += p.z; s.w += p.w;
        }
        float s0 = s.x * 0.03125f, s1 = s.y * 0.03125f;
        float s2 = s.z * 0.03125f, s3 = s.w * 0.03125f;
        const int keyg = j * 32 + c0;
        const int rowg = q0 + rr;
        if (keyg + 0 > rowg) s0 = -INFINITY;
        if (keyg + 1 > rowg) s1 = -INFINITY;
        if (keyg + 2 > rowg) s2 = -INFINITY;
        if (keyg + 3 > rowg) s3 = -INFINITY;
        float mx = fmaxf(fmaxf(s0, s1), fmaxf(s2, s3));
#pragma unroll
        for (int off = 1; off < 8; off <<= 1) mx = fmaxf(mx, __shfl_xor(mx, off));
        const float mold = mS[rr];
        const float mnew = fmaxf(mold, mx);
        const float p0 = __expf(s0 - mnew), p1 = __expf(s1 - mnew);
        const float p2 = __expf(s2 - mnew), p3 = __expf(s3 - mnew);
        float rs = p0 + p1 + p2 + p3;
#pragma unroll
        for (int off = 1; off < 8; off <<= 1) rs += __shfl_xor(rs, off);
        const float alpha = __expf(mold - mnew);
        if ((tid & 7) == 0) {
            mS[rr] = mnew;
            lS[rr] = lS[rr] * alpha + rs;
            aS[rr] = alpha;
        }
        *(uint2*)&Pl[rr * 40 + c0] = pack4bf(p0, p1, p2, p3);
        __syncthreads();

        // ---- rescale o by alpha (read aS per-mt to cap registers) ----
#pragma unroll
        for (int mt = 0; mt < 4; ++mt) {
            float a0 = aS[mt * 16 + quad * 4 + 0];
            float a1 = aS[mt * 16 + quad * 4 + 1];
            float a2 = aS[mt * 16 + quad * 4 + 2];
            float a3 = aS[mt * 16 + quad * 4 + 3];
#pragma unroll
            for (int nt = 0; nt < 8; ++nt) {
                o[mt][nt][0] *= a0; o[mt][nt][1] *= a1;
                o[mt][nt][2] *= a2; o[mt][nt][3] *= a3;
            }
        }
        // ---- PV: P (A-frag from LDS) x V-chunk ----
        short8 pa[4];
#pragma unroll
        for (int mt = 0; mt < 4; ++mt)
            pa[mt] = *(const short8*)&Pl[(mt * 16 + l16) * 40 + quad * 8];
#pragma unroll
        for (int nt = 0; nt < 8; ++nt)
#pragma unroll
            for (int mt = 0; mt < 4; ++mt)
                o[mt][nt] = __builtin_amdgcn_mfma_f32_16x16x32_bf16(
                    pa[mt], vb[nt], o[mt][nt], 0, 0, 0);
        // next iter's Sp writes are pre-barrier-1; Pl/aS reads here are safe.
    }

#pragma unroll
    for (int mt = 0; mt < 4; ++mt) {
        float li0 = 1.f / lS[mt * 16 + quad * 4 + 0];
        float li1 = 1.f / lS[mt * 16 + quad * 4 + 1];
        float li2 = 1.f / lS[mt * 16 + quad * 4 + 2];
        float li3 = 1.f / lS[mt * 16 + quad * 4 + 3];
#pragma unroll
        for (int nt = 0; nt < 8; ++nt) {
            const size_t base = (qrow + q0 + mt * 16 + quad * 4) * DIM + wave * 128 + nt * 16 + l16;
            out[base]           = o[mt][nt][0] * li0;
            out[base + DIM]     = o[mt][nt][1] * li1;
            out[base + 2 * DIM] = o[mt][nt][2] * li2;
            out[base + 3 * DIM] = o[mt][nt][3] * li3;
        }
    }
}

extern "C" void kernel_launch(void* const* d_in, const int* in_sizes, int n_in,
                              void* d_out, int out_size, void* d_ws, size_t ws_size,
                              hipStream_t stream) {
    const float* query = (const float*)d_in[0];
    const float* key   = (const float*)d_in[1];
    const float* value = (const float*)d_in[2];
    const float* ctx   = (const float*)d_in[3];
    const float* Wq    = (const float*)d_in[4];
    const float* bq    = (const float*)d_in[5];
    const float* Wk    = (const float*)d_in[6];
    const float* bk    = (const float*)d_in[7];
    const float* Wv    = (const float*)d_in[8];
    const float* bv    = (const float*)d_in[9];

    // workspace layout (bf16), with aliasing to stay small:
    //  A = xq  -> later overwritten with kw (projk output)
    //  B = xk
    //  C = xv  -> later overwritten with qw (projq output)
    //  D = vw  (vT)
    ushort_t* A = (ushort_t*)d_ws;
    ushort_t* B = A + (size_t)BSD;
    ushort_t* C = B + (size_t)BSD;
    ushort_t* D = C + (size_t)BSD;
    ushort_t* wqb = D + (size_t)BSD;
    ushort_t* wkb = wqb + (size_t)DD;
    ushort_t* wvb = wkb + (size_t)DD;
    float* out = (float*)d_out;

    {   // convert everything to bf16 (ctx folded into q/k)
        const long total = 3L * (BSD / 4) + 3L * (DD / 4);
        convert_kernel<<<dim3((unsigned)(total / 256)), dim3(256), 0, stream>>>(
            query, key, value, ctx, Wq, Wk, Wv, A, B, C, wqb, wkb, wvb);
    }

    const dim3 pg((BATCH * SEQ) / 128, DIM / 128);  // (128, 8)
    // order matters for aliasing: v first (reads C), then q (writes C), then k (writes A)
    gemm_bf16<<<pg, dim3(256), 0, stream>>>(C, wvb, bv, D, 1);  // vT
    gemm_bf16<<<pg, dim3(256), 0, stream>>>(A, wqb, bq, C, 0);  // q  (xv dead)
    gemm_bf16<<<pg, dim3(256), 0, stream>>>(B, wkb, bk, A, 0);  // k  (xq dead)

    attn_kernel<<<dim3(BATCH * (SEQ / 64)), dim3(512), 0, stream>>>(C, A, D, out);
}